// Round 5
// baseline (236.605 us; speedup 1.0000x reference)
//
#include <hip/hip_runtime.h>

// SSIM (B=16, C=3, H=W=512, fp32) -> scalar mean.
// v5: 4 LDS planes (x1, x2, x1^2+x2^2, x1*x2 -- sigma terms only ever appear
// summed), derived-value register ring (products computed once per loaded
// row), fully unrolled step loop (ring shift = register rename), double-
// buffered LDS (1 barrier/step), halo-only LDS init, rcp+NR division.
// Per-block partials in d_ws, final double reduce -> d_out[0].

#define IMG_H 512
#define IMG_W 512
#define N_IMG 48                    // B*C
#define WS 11
#define PAD 5
#define CHUNK 16                    // output rows per block
#define NCHUNK (IMG_H / CHUNK)      // 32
#define NBLK (N_IMG * NCHUNK)       // 1536
#define RING 12                     // rows held in registers
#define OFF 6                       // column c stored at element OFF+c
#define VSW 524                     // max element read = 2*255+13 = 523

__global__ __launch_bounds__(256, 3) void ssim_partial_kernel(
    const float* __restrict__ img1,
    const float* __restrict__ img2,
    const float* __restrict__ window,
    float* __restrict__ partial)
{
    __shared__ float vs[2][2][4][VSW];  // [buf][staged row][plane][element]
    __shared__ float wred[4];

    const int tid = threadIdx.x;
    const int bc  = blockIdx.x;              // image*channel 0..47
    const int r0  = blockIdx.y * CHUNK;
    const int col = tid * 2;                 // owned columns: col, col+1

    // 1-D gaussian from window row 5: w2d[5][j] = g5*g[j], g5 = sqrt(w2d[5][5]).
    float g[WS];
    {
        const float g5  = sqrtf(window[5 * WS + 5]);
        const float inv = 1.0f / g5;
#pragma unroll
        for (int j = 0; j < WS; ++j) g[j] = window[5 * WS + j] * inv;
    }
    const float C1v = 0.01f * 0.01f;
    const float C2v = 0.03f * 0.03f;

    const float* __restrict__ p1 = img1 + (size_t)bc * (IMG_H * IMG_W);
    const float* __restrict__ p2 = img2 + (size_t)bc * (IMG_H * IMG_W);

    // zero only halo elements (0..5 and 518..523 of each plane-row);
    // interior elements 6..517 are fully overwritten every step.
    for (int i = tid; i < 2 * 2 * 4 * 12; i += 256) {   // 192 stores
        const int pr = i / 12, h = i % 12;
        const int e  = (h < OFF) ? h : (512 + h);
        (&vs[0][0][0][0])[pr * VSW + e] = 0.0f;
    }
    __syncthreads();

    // derived ring: x1, x2, s = x1^2+x2^2, p = x1*x2 for the 2 owned columns.
    // invariant (after the shift in step with base row R): slot i holds row R-5+i.
    float r1a[RING], r1b[RING], r2a[RING], r2b[RING];
    float rsa[RING], rsb[RING], rpa[RING], rpb[RING];
#pragma unroll
    for (int i = 0; i < RING; ++i) {
        r1a[i]=0.f; r1b[i]=0.f; r2a[i]=0.f; r2b[i]=0.f;
        rsa[i]=0.f; rsb[i]=0.f; rpa[i]=0.f; rpb[i]=0.f;
    }

    // warm-up: slots 2..11 <- rows r0-5 .. r0+4 (after first shift -> slots 0..9)
#pragma unroll
    for (int i = 0; i < 10; ++i) {
        const int rr = r0 - PAD + i;
        float a1=0.f, b1=0.f, a2=0.f, b2=0.f;
        if (rr >= 0 && rr < IMG_H) {               // uniform branch
            const float2 u1 = *(const float2*)(p1 + rr * IMG_W + col);
            const float2 u2 = *(const float2*)(p2 + rr * IMG_W + col);
            a1 = u1.x; b1 = u1.y; a2 = u2.x; b2 = u2.y;
        }
        r1a[2+i] = a1; r1b[2+i] = b1; r2a[2+i] = a2; r2b[2+i] = b2;
        rsa[2+i] = fmaf(a1, a1, a2 * a2);
        rsb[2+i] = fmaf(b1, b1, b2 * b2);
        rpa[2+i] = a1 * a2;
        rpb[2+i] = b1 * b2;
    }

    float acc = 0.0f;

#pragma unroll
    for (int step = 0; step < CHUNK / 2; ++step) {
        const int R   = r0 + step * 2;         // output rows R, R+1 this step
        const int buf = step & 1;

        // shift ring by 2 (renamed away by full unroll)
#pragma unroll
        for (int i = 0; i < RING - 2; ++i) {
            r1a[i]=r1a[i+2]; r1b[i]=r1b[i+2]; r2a[i]=r2a[i+2]; r2b[i]=r2b[i+2];
            rsa[i]=rsa[i+2]; rsb[i]=rsb[i+2]; rpa[i]=rpa[i+2]; rpb[i]=rpb[i+2];
        }
        // load rows R+5, R+6 -> slots 10, 11 (slot i = row R-5+i)
#pragma unroll
        for (int j = 0; j < 2; ++j) {
            const int rr = R + PAD + j;
            float a1=0.f, b1=0.f, a2=0.f, b2=0.f;
            if (rr < IMG_H) {                  // rr >= 0 always; uniform branch
                const float2 u1 = *(const float2*)(p1 + rr * IMG_W + col);
                const float2 u2 = *(const float2*)(p2 + rr * IMG_W + col);
                a1 = u1.x; b1 = u1.y; a2 = u2.x; b2 = u2.y;
            }
            r1a[10+j] = a1; r1b[10+j] = b1; r2a[10+j] = a2; r2b[10+j] = b2;
            rsa[10+j] = fmaf(a1, a1, a2 * a2);
            rsb[10+j] = fmaf(b1, b1, b2 * b2);
            rpa[10+j] = a1 * a2;
            rpb[10+j] = b1 * b2;
        }

        // vertical gaussian sums for output rows R (j=0), R+1 (j=1); stage to LDS
#pragma unroll
        for (int j = 0; j < 2; ++j) {
            float v1a=0.f, v2a=0.f, vsa_=0.f, vpa_=0.f;
            float v1b=0.f, v2b=0.f, vsb_=0.f, vpb_=0.f;
#pragma unroll
            for (int i = 0; i < WS; ++i) {
                const float w = g[i];
                v1a = fmaf(w, r1a[i+j], v1a);
                v2a = fmaf(w, r2a[i+j], v2a);
                vsa_ = fmaf(w, rsa[i+j], vsa_);
                vpa_ = fmaf(w, rpa[i+j], vpa_);
                v1b = fmaf(w, r1b[i+j], v1b);
                v2b = fmaf(w, r2b[i+j], v2b);
                vsb_ = fmaf(w, rsb[i+j], vsb_);
                vpb_ = fmaf(w, rpb[i+j], vpb_);
            }
            *(float2*)&vs[buf][j][0][OFF + col] = make_float2(v1a,  v1b);
            *(float2*)&vs[buf][j][1][OFF + col] = make_float2(v2a,  v2b);
            *(float2*)&vs[buf][j][2][OFF + col] = make_float2(vsa_, vsb_);
            *(float2*)&vs[buf][j][3][OFF + col] = make_float2(vpa_, vpb_);
        }
        __syncthreads();   // writes visible; reads of buf^1 (prev step) done
                           // before its next overwrite (2 steps away, ordered
                           // by the next step's barrier)

        // horizontal conv + SSIM: 4 px = cols {col, col+1} x rows {R, R+1}.
        // elements 2t..2t+13 as 7 float2: 8B lane stride (2-way alias, free).
#pragma unroll
        for (int j = 0; j < 2; ++j) {
            float hv[2][4];
#pragma unroll
            for (int p = 0; p < 4; ++p) {
                const float2* q = (const float2*)&vs[buf][j][p][col];
                const float2 f0=q[0], f1=q[1], f2=q[2], f3=q[3],
                             f4=q[4], f5=q[5], f6=q[6];
                const float b[14] = {f0.x,f0.y,f1.x,f1.y,f2.x,f2.y,f3.x,f3.y,
                                     f4.x,f4.y,f5.x,f5.y,f6.x,f6.y};
                float s0 = 0.f, s1 = 0.f;
#pragma unroll
                for (int i = 0; i < WS; ++i) {
                    s0 = fmaf(g[i], b[i+1], s0);   // px col
                    s1 = fmaf(g[i], b[i+2], s1);   // px col+1
                }
                hv[0][p] = s0; hv[1][p] = s1;
            }
#pragma unroll
            for (int k = 0; k < 2; ++k) {
                const float mu1 = hv[k][0], mu2 = hv[k][1];
                const float hs  = hv[k][2], hp  = hv[k][3];
                const float mu1s = mu1 * mu1;
                const float mu2s = mu2 * mu2;
                const float mu12 = mu1 * mu2;
                const float sgs  = hs - mu1s - mu2s;   // sigma1^2 + sigma2^2
                const float sg12 = hp - mu12;
                const float num  = (2.f * mu12 + C1v) * (2.f * sg12 + C2v);
                const float den  = (mu1s + mu2s + C1v) * (sgs + C2v);
                float r = __builtin_amdgcn_rcpf(den);
                r = r * fmaf(-den, r, 2.0f);           // Newton: ~1 ulp
                acc = fmaf(num, r, acc);
            }
        }
        // no trailing barrier: next step writes the other buffer; the write
        // of THIS buffer happens 2 steps later, ordered by the intervening
        // __syncthreads.
    }

    // block reduction
#pragma unroll
    for (int off = 32; off > 0; off >>= 1)
        acc += __shfl_down(acc, off);
    if ((tid & 63) == 0) wred[tid >> 6] = acc;
    __syncthreads();
    if (tid == 0) {
        const float s = wred[0] + wred[1] + wred[2] + wred[3];
        partial[blockIdx.y * N_IMG + blockIdx.x] = s;
    }
}

__global__ __launch_bounds__(256) void ssim_reduce_kernel(
    const float* __restrict__ partial, float* __restrict__ out)
{
    __shared__ double wred[4];
    const int tid = threadIdx.x;
    double s = 0.0;
    for (int i = tid; i < NBLK; i += 256) s += (double)partial[i];
#pragma unroll
    for (int off = 32; off > 0; off >>= 1)
        s += __shfl_down(s, off);
    if ((tid & 63) == 0) wred[tid >> 6] = s;
    __syncthreads();
    if (tid == 0) {
        const double total = wred[0] + wred[1] + wred[2] + wred[3];
        out[0] = (float)(total / (double)((size_t)N_IMG * IMG_H * IMG_W));
    }
}

extern "C" void kernel_launch(void* const* d_in, const int* in_sizes, int n_in,
                              void* d_out, int out_size, void* d_ws, size_t ws_size,
                              hipStream_t stream) {
    const float* img1   = (const float*)d_in[0];
    const float* img2   = (const float*)d_in[1];
    const float* window = (const float*)d_in[2];
    float* out     = (float*)d_out;
    float* partial = (float*)d_ws;   // NBLK floats, all written every call

    dim3 grid(N_IMG, NCHUNK);
    ssim_partial_kernel<<<grid, 256, 0, stream>>>(img1, img2, window, partial);
    ssim_reduce_kernel<<<1, 256, 0, stream>>>(partial, out);
}

// Round 6
// 155.776 us; speedup vs baseline: 1.5189x; 1.5189x over previous
//
#include <hip/hip_runtime.h>

// SSIM (B=16, C=3, H=W=512, fp32) -> scalar mean.
// v6: v4 structure (proven 76us) + safe subset of v5:
//   - 4 LDS planes: mu1, mu2, conv(x1^2+x2^2), conv(x1*x2)  (HW-verified algebra)
//   - rcp + 1 Newton step for the SSIM division
//   - fused reduction: per-block atomicAdd of pre-scaled partial into d_out[0]
//     (d_out zeroed via hipMemsetAsync on stream; fp32 atomic jitter ~2e-6 rel)
// NOT carried from v5 (caused scratch spills, WRITE_SIZE 131MB): full unroll
// of the step loop, derived-value ring, double-buffered LDS, launch_bounds 3.

#define IMG_H 512
#define IMG_W 512
#define N_IMG 48                    // B*C
#define WS 11
#define PAD 5
#define CHUNK 16                    // output rows per block
#define NCHUNK (IMG_H / CHUNK)      // 32
#define RING 12                     // rows held in registers
#define OFF 6                       // column c stored at element OFF+c
#define VSW 524                     // max element read = 2*255+13 = 523
#define INV_NPX (1.0f / (48.0f * 512.0f * 512.0f))

__global__ __launch_bounds__(256, 4) void ssim_partial_kernel(
    const float* __restrict__ img1,
    const float* __restrict__ img2,
    const float* __restrict__ window,
    float* __restrict__ out)
{
    __shared__ float vs[2][4][VSW];   // [staged row][plane][element]
    __shared__ float wred[4];

    const int tid = threadIdx.x;
    const int bc  = blockIdx.x;              // image*channel 0..47
    const int r0  = blockIdx.y * CHUNK;
    const int col = tid * 2;                 // owned columns: col, col+1

    // 1-D gaussian from window row 5: w2d[5][j] = g5*g[j], g5 = sqrt(w2d[5][5]).
    float g[WS];
    {
        const float g5  = sqrtf(window[5 * WS + 5]);
        const float inv = 1.0f / g5;
#pragma unroll
        for (int j = 0; j < WS; ++j) g[j] = window[5 * WS + j] * inv;
    }
    const float C1v = 0.01f * 0.01f;
    const float C2v = 0.03f * 0.03f;

    const float* __restrict__ p1 = img1 + (size_t)bc * (IMG_H * IMG_W);
    const float* __restrict__ p2 = img2 + (size_t)bc * (IMG_H * IMG_W);

    // zero entire vs region once; halo/pad elements stay zero forever
    {
        float* vflat = &vs[0][0][0];
        for (int i = tid; i < 2 * 4 * VSW; i += 256) vflat[i] = 0.0f;
    }
    __syncthreads();

    // raw register ring: x1,x2 for the 2 owned columns.
    // invariant (after the shift in step with base row R): slot i holds row R-5+i.
    float rx1a[RING], rx1b[RING], rx2a[RING], rx2b[RING];
#pragma unroll
    for (int i = 0; i < RING; ++i) { rx1a[i]=0.f; rx1b[i]=0.f; rx2a[i]=0.f; rx2b[i]=0.f; }

    // warm-up: slots 2..11 <- rows r0-5 .. r0+4 (after first shift -> slots 0..9)
#pragma unroll
    for (int i = 0; i < 10; ++i) {
        const int rr = r0 - PAD + i;
        float a0=0.f, a1=0.f, b0=0.f, b1=0.f;
        if (rr >= 0 && rr < IMG_H) {               // uniform branch
            const float2 u1 = *(const float2*)(p1 + rr * IMG_W + col);
            const float2 u2 = *(const float2*)(p2 + rr * IMG_W + col);
            a0 = u1.x; a1 = u1.y; b0 = u2.x; b1 = u2.y;
        }
        rx1a[2+i] = a0; rx1b[2+i] = a1; rx2a[2+i] = b0; rx2b[2+i] = b1;
    }

    float acc = 0.0f;

    for (int step = 0; step < CHUNK / 2; ++step) {
        const int R = r0 + step * 2;           // output rows R, R+1 this step

        // shift ring by 2
#pragma unroll
        for (int i = 0; i < RING - 2; ++i) {
            rx1a[i] = rx1a[i+2]; rx1b[i] = rx1b[i+2];
            rx2a[i] = rx2a[i+2]; rx2b[i] = rx2b[i+2];
        }
        // load rows R+5, R+6 -> slots 10, 11 (slot i = row R-5+i)
#pragma unroll
        for (int j = 0; j < 2; ++j) {
            const int rr = R + PAD + j;
            float a0=0.f, a1=0.f, b0=0.f, b1=0.f;
            if (rr < IMG_H) {                  // rr >= 0 always; uniform branch
                const float2 u1 = *(const float2*)(p1 + rr * IMG_W + col);
                const float2 u2 = *(const float2*)(p2 + rr * IMG_W + col);
                a0 = u1.x; a1 = u1.y; b0 = u2.x; b1 = u2.y;
            }
            rx1a[10+j] = a0; rx1b[10+j] = a1; rx2a[10+j] = b0; rx2b[10+j] = b1;
        }

        // vertical gaussian sums (4 planes) for rows R (j=0), R+1 (j=1) -> LDS
#pragma unroll
        for (int j = 0; j < 2; ++j) {
            float v1a=0.f, v2a=0.f, vsa=0.f, vpa=0.f;
            float v1b=0.f, v2b=0.f, vsb=0.f, vpb=0.f;
#pragma unroll
            for (int i = 0; i < WS; ++i) {
                const float w  = g[i];
                const float x1 = rx1a[i+j], x2 = rx2a[i+j];
                const float t1 = w * x1,    t2 = w * x2;
                v1a += t1; v2a += t2;
                vsa = fmaf(t1, x1, fmaf(t2, x2, vsa));   // w*(x1^2+x2^2)
                vpa = fmaf(t1, x2, vpa);                 // w*(x1*x2)
                const float y1 = rx1b[i+j], y2 = rx2b[i+j];
                const float s1 = w * y1,    s2 = w * y2;
                v1b += s1; v2b += s2;
                vsb = fmaf(s1, y1, fmaf(s2, y2, vsb));
                vpb = fmaf(s1, y2, vpb);
            }
            *(float2*)&vs[j][0][OFF + col] = make_float2(v1a, v1b);
            *(float2*)&vs[j][1][OFF + col] = make_float2(v2a, v2b);
            *(float2*)&vs[j][2][OFF + col] = make_float2(vsa, vsb);
            *(float2*)&vs[j][3][OFF + col] = make_float2(vpa, vpb);
        }
        __syncthreads();

        // horizontal conv + SSIM: 4 px = cols {col, col+1} x rows {R, R+1}.
        // elements 2t..2t+13 as 7 float2: 8B lane stride (2-way alias, cheap).
#pragma unroll
        for (int j = 0; j < 2; ++j) {
            float hv[2][4];
#pragma unroll
            for (int p = 0; p < 4; ++p) {
                const float2* q = (const float2*)&vs[j][p][col];
                const float2 f0=q[0], f1=q[1], f2=q[2], f3=q[3],
                             f4=q[4], f5=q[5], f6=q[6];
                const float b[14] = {f0.x,f0.y,f1.x,f1.y,f2.x,f2.y,f3.x,f3.y,
                                     f4.x,f4.y,f5.x,f5.y,f6.x,f6.y};
                float s0 = 0.f, s1 = 0.f;
#pragma unroll
                for (int i = 0; i < WS; ++i) {
                    s0 = fmaf(g[i], b[i+1], s0);   // px col
                    s1 = fmaf(g[i], b[i+2], s1);   // px col+1
                }
                hv[0][p] = s0; hv[1][p] = s1;
            }
#pragma unroll
            for (int k = 0; k < 2; ++k) {
                const float mu1 = hv[k][0], mu2 = hv[k][1];
                const float hs  = hv[k][2], hp  = hv[k][3];
                const float mu1s = mu1 * mu1;
                const float mu2s = mu2 * mu2;
                const float mu12 = mu1 * mu2;
                const float sgs  = hs - mu1s - mu2s;   // sigma1^2 + sigma2^2
                const float sg12 = hp - mu12;
                const float num  = (2.f * mu12 + C1v) * (2.f * sg12 + C2v);
                const float den  = (mu1s + mu2s + C1v) * (sgs + C2v);
                float r = __builtin_amdgcn_rcpf(den);
                r = r * fmaf(-den, r, 2.0f);           // Newton -> ~1 ulp
                acc = fmaf(num, r, acc);
            }
        }
        __syncthreads();   // before vs is overwritten next step
    }

    // block reduction -> single atomic per block (pre-scaled by 1/Npx)
#pragma unroll
    for (int off = 32; off > 0; off >>= 1)
        acc += __shfl_down(acc, off);
    if ((tid & 63) == 0) wred[tid >> 6] = acc;
    __syncthreads();
    if (tid == 0) {
        const float s = (wred[0] + wred[1]) + (wred[2] + wred[3]);
        atomicAdd(out, s * INV_NPX);
    }
}

extern "C" void kernel_launch(void* const* d_in, const int* in_sizes, int n_in,
                              void* d_out, int out_size, void* d_ws, size_t ws_size,
                              hipStream_t stream) {
    const float* img1   = (const float*)d_in[0];
    const float* img2   = (const float*)d_in[1];
    const float* window = (const float*)d_in[2];
    float* out = (float*)d_out;

    hipMemsetAsync(out, 0, sizeof(float), stream);   // graph-capturable
    dim3 grid(N_IMG, NCHUNK);
    ssim_partial_kernel<<<grid, 256, 0, stream>>>(img1, img2, window, out);
}

// Round 7
// 146.600 us; speedup vs baseline: 1.6139x; 1.0626x over previous
//
#include <hip/hip_runtime.h>

// SSIM (B=16, C=3, H=W=512, fp32) -> scalar mean.
// v7: packed-fp32 (v_pk_fma_f32) everywhere + row-pair LDS layout.
//  - LDS stores, per plane, one float2 {row0,row1} per column, address-swizzled
//    (addr = 8E + 8*(E>>3)) so the 16B lane stride aliases only 2-way (free).
//  - Horizontal conv: 12 ds_read_b64 per plane -> 22 pk_fma per plane (aligned
//    packed operands, no unpack array).
//  - Vertical conv: register ring of raw x1,x2 as float2 (col pair), packed
//    taps with s,p recomputed per tap (keeps ring at 48 VGPR).
//  - Single LDS buffer, 2 barriers/step (proven v6 structure), CHUNK=16.
//  - Fused reduction: per-block atomicAdd of pre-scaled partial into d_out[0].

typedef float v2f __attribute__((ext_vector_type(2)));

#define IMG_H 512
#define IMG_W 512
#define N_IMG 48                    // B*C
#define WS 11
#define PAD 5
#define CHUNK 16                    // output rows per block
#define NCHUNK (IMG_H / CHUNK)      // 32
#define RING 12                     // rows held in registers
#define PLANE_B 4736                // bytes per plane (max swizzled off 4712)
#define INV_NPX (1.0f / (48.0f * 512.0f * 512.0f))

// swizzled byte offset of element E (E = col + 6, one float2 per element)
__device__ __forceinline__ unsigned swz(int E) { return 8u * E + 8u * (E >> 3); }

__device__ __forceinline__ v2f vfma(v2f a, v2f b, v2f c) {
    return __builtin_elementwise_fma(a, b, c);
}

__global__ __launch_bounds__(256) void ssim_partial_kernel(
    const float* __restrict__ img1,
    const float* __restrict__ img2,
    const float* __restrict__ window,
    float* __restrict__ out)
{
    __shared__ __align__(16) char lds[4 * PLANE_B];
    __shared__ float wred[4];
#define LDSE(p, off) (*(v2f*)(lds + (p) * PLANE_B + (off)))

    const int tid = threadIdx.x;
    const int bc  = blockIdx.x;              // image*channel 0..47
    const int r0  = blockIdx.y * CHUNK;
    const int col = tid * 2;                 // owned columns: col, col+1

    // 1-D gaussian from window row 5: w2d[5][j] = g5*g[j], g5 = sqrt(w2d[5][5]).
    float g[WS];
    {
        const float g5  = sqrtf(window[5 * WS + 5]);
        const float inv = 1.0f / g5;
#pragma unroll
        for (int j = 0; j < WS; ++j) g[j] = window[5 * WS + j] * inv;
    }
    const float C1v = 0.01f * 0.01f;
    const float C2v = 0.03f * 0.03f;

    const float* __restrict__ p1 = img1 + (size_t)bc * (IMG_H * IMG_W);
    const float* __restrict__ p2 = img2 + (size_t)bc * (IMG_H * IMG_W);

    // precomputed step-invariant LDS byte offsets
    unsigned roff[12];                        // reads: E = 2t+1 .. 2t+12
#pragma unroll
    for (int m = 0; m < 12; ++m) roff[m] = swz(2 * tid + 1 + m);
    const unsigned woffA = swz(2 * tid + 6);  // write col,   E = 2t+6
    const unsigned woffB = swz(2 * tid + 7);  // write col+1, E = 2t+7

    // zero halo elements once: E in {0..5, 518..523} per plane (48 total)
    for (int i = tid; i < 48; i += 256) {
        const int p = i / 12, h = i % 12;
        const int E = (h < 6) ? h : (512 + h);
        LDSE(p, swz(E)) = (v2f)(0.0f);
    }
    __syncthreads();

    // raw register ring (packed col pair): slot i holds row R-5+i after shift
    v2f rx1[RING], rx2[RING];
#pragma unroll
    for (int i = 0; i < RING; ++i) { rx1[i] = (v2f)(0.0f); rx2[i] = (v2f)(0.0f); }

    // warm-up: slots 2..11 <- rows r0-5 .. r0+4
#pragma unroll
    for (int i = 0; i < 10; ++i) {
        const int rr = r0 - PAD + i;
        v2f u1 = (v2f)(0.0f), u2 = (v2f)(0.0f);
        if (rr >= 0 && rr < IMG_H) {               // uniform branch
            u1 = *(const v2f*)(p1 + rr * IMG_W + col);
            u2 = *(const v2f*)(p2 + rr * IMG_W + col);
        }
        rx1[2 + i] = u1; rx2[2 + i] = u2;
    }

    float acc = 0.0f;

    for (int step = 0; step < CHUNK / 2; ++step) {
        const int R = r0 + step * 2;           // output rows R, R+1 this step

        // shift ring by 2
#pragma unroll
        for (int i = 0; i < RING - 2; ++i) { rx1[i] = rx1[i + 2]; rx2[i] = rx2[i + 2]; }
        // load rows R+5, R+6 -> slots 10, 11
#pragma unroll
        for (int j = 0; j < 2; ++j) {
            const int rr = R + PAD + j;
            v2f u1 = (v2f)(0.0f), u2 = (v2f)(0.0f);
            if (rr < IMG_H) {                  // uniform branch
                u1 = *(const v2f*)(p1 + rr * IMG_W + col);
                u2 = *(const v2f*)(p2 + rr * IMG_W + col);
            }
            rx1[10 + j] = u1; rx2[10 + j] = u2;
        }

        // vertical gaussian sums, packed over the col pair, rows j=0,1
        v2f a1_0 = (v2f)(0.f), a2_0 = (v2f)(0.f), aS_0 = (v2f)(0.f), aP_0 = (v2f)(0.f);
        v2f a1_1 = (v2f)(0.f), a2_1 = (v2f)(0.f), aS_1 = (v2f)(0.f), aP_1 = (v2f)(0.f);
#pragma unroll
        for (int i = 0; i < WS; ++i) {
            const float w = g[i];
            {
                const v2f X1 = rx1[i], X2 = rx2[i];
                a1_0 = vfma((v2f)(w), X1, a1_0);
                a2_0 = vfma((v2f)(w), X2, a2_0);
                aS_0 = vfma((v2f)(w), vfma(X1, X1, X2 * X2), aS_0);
                aP_0 = vfma((v2f)(w), X1 * X2, aP_0);
            }
            {
                const v2f X1 = rx1[i + 1], X2 = rx2[i + 1];
                a1_1 = vfma((v2f)(w), X1, a1_1);
                a2_1 = vfma((v2f)(w), X2, a2_1);
                aS_1 = vfma((v2f)(w), vfma(X1, X1, X2 * X2), aS_1);
                aP_1 = vfma((v2f)(w), X1 * X2, aP_1);
            }
        }
        // repack to {row0,row1} per column and store: planes 0..3
        LDSE(0, woffA) = (v2f){a1_0.x, a1_1.x}; LDSE(0, woffB) = (v2f){a1_0.y, a1_1.y};
        LDSE(1, woffA) = (v2f){a2_0.x, a2_1.x}; LDSE(1, woffB) = (v2f){a2_0.y, a2_1.y};
        LDSE(2, woffA) = (v2f){aS_0.x, aS_1.x}; LDSE(2, woffB) = (v2f){aS_0.y, aS_1.y};
        LDSE(3, woffA) = (v2f){aP_0.x, aP_1.x}; LDSE(3, woffB) = (v2f){aP_0.y, aP_1.y};
        __syncthreads();

        // horizontal conv, packed over {row0,row1}: cols col (A) and col+1 (B)
        v2f hA[4], hB[4];
#pragma unroll
        for (int p = 0; p < 4; ++p) {
            v2f r[12];
#pragma unroll
            for (int m = 0; m < 12; ++m) r[m] = LDSE(p, roff[m]);
            v2f sA = (v2f)(0.f), sB = (v2f)(0.f);
#pragma unroll
            for (int i = 0; i < WS; ++i) {
                sA = vfma((v2f)(g[i]), r[i],     sA);
                sB = vfma((v2f)(g[i]), r[i + 1], sB);
            }
            hA[p] = sA; hB[p] = sB;
        }
        // SSIM, packed over {row0,row1}, then scalar rcp+NR per lane-half
#pragma unroll
        for (int k = 0; k < 2; ++k) {
            const v2f mu1 = k ? hB[0] : hA[0];
            const v2f mu2 = k ? hB[1] : hA[1];
            const v2f hs  = k ? hB[2] : hA[2];
            const v2f hp  = k ? hB[3] : hA[3];
            const v2f mu1s = mu1 * mu1;
            const v2f mu2s = mu2 * mu2;
            const v2f mu12 = mu1 * mu2;
            const v2f sgs  = hs - mu1s - mu2s;       // sigma1^2 + sigma2^2
            const v2f sg12 = hp - mu12;
            const v2f num  = (2.f * mu12 + (v2f)(C1v)) * (2.f * sg12 + (v2f)(C2v));
            const v2f den  = (mu1s + mu2s + (v2f)(C1v)) * (sgs + (v2f)(C2v));
            v2f r = {__builtin_amdgcn_rcpf(den.x), __builtin_amdgcn_rcpf(den.y)};
            r = r * vfma(-den, r, (v2f)(2.0f));      // Newton -> ~1 ulp
            acc = fmaf(num.x, r.x, acc);
            acc = fmaf(num.y, r.y, acc);
        }
        __syncthreads();   // before LDS is overwritten next step
    }

    // block reduction -> single atomic per block (pre-scaled by 1/Npx)
#pragma unroll
    for (int off = 32; off > 0; off >>= 1)
        acc += __shfl_down(acc, off);
    if ((tid & 63) == 0) wred[tid >> 6] = acc;
    __syncthreads();
    if (tid == 0) {
        const float s = (wred[0] + wred[1]) + (wred[2] + wred[3]);
        atomicAdd(out, s * INV_NPX);
    }
}

extern "C" void kernel_launch(void* const* d_in, const int* in_sizes, int n_in,
                              void* d_out, int out_size, void* d_ws, size_t ws_size,
                              hipStream_t stream) {
    const float* img1   = (const float*)d_in[0];
    const float* img2   = (const float*)d_in[1];
    const float* window = (const float*)d_in[2];
    float* out = (float*)d_out;

    hipMemsetAsync(out, 0, sizeof(float), stream);   // graph-capturable
    dim3 grid(N_IMG, NCHUNK);
    ssim_partial_kernel<<<grid, 256, 0, stream>>>(img1, img2, window, out);
}

// Round 8
// 141.999 us; speedup vs baseline: 1.6662x; 1.0324x over previous
//
#include <hip/hip_runtime.h>

// SSIM (B=16, C=3, H=W=512, fp32) -> scalar mean.
// v8: 4-row steps + col-quad horizontal ownership to cut LDS traffic.
//  - Vertical: thread owns col pair {2t,2t+1}, register ring of 14 raw rows,
//    4 planes x 4 rows packed accumulators (slot products CSE'd by compiler),
//    16 b64 writes/step.
//  - Horizontal+SSIM: thread = (row-pair tid>>7, col-quad tid&127 -> 4 cols):
//    56 b64 reads per 4 rows (14 elements x 4 planes, halo amortized over
//    4 cols), conv + SSIM fully in-thread (packed over the row pair).
//  - XOR element swizzle P = E ^ (((E>>4)&7)<<1): parity-breaking, gives
//    ~4 dwords/bank/phase for both the 16B-stride writes and 32B-stride reads.
//  - 2 barriers per 4 rows (8/block). Fused atomicAdd reduction.

typedef float v2f __attribute__((ext_vector_type(2)));

#define IMG_H 512
#define IMG_W 512
#define N_IMG 48                    // B*C
#define WS 11
#define PAD 5
#define CHUNK 16                    // output rows per block
#define NCHUNK (IMG_H / CHUNK)      // 32
#define RING 14                     // rows held in registers
#define PLANE_B 4224                // bytes per (pair,plane) region (max P=523 -> 4192)
#define INV_NPX (1.0f / (48.0f * 512.0f * 512.0f))

// swizzled byte offset of element E (element = 8B v2f {row_even,row_odd})
__device__ __forceinline__ unsigned swz8(int E) {
    return (unsigned)((E ^ (((E >> 4) & 7) << 1)) * 8);
}
__device__ __forceinline__ v2f vfma(v2f a, v2f b, v2f c) {
    return __builtin_elementwise_fma(a, b, c);
}

__global__ __launch_bounds__(256, 3) void ssim_partial_kernel(
    const float* __restrict__ img1,
    const float* __restrict__ img2,
    const float* __restrict__ window,
    float* __restrict__ out)
{
    __shared__ __align__(16) char lds[8 * PLANE_B];   // region (pair*4+plane)
    __shared__ float wred[4];

    const int tid = threadIdx.x;
    const int bc  = blockIdx.x;              // image*channel 0..47
    const int r0  = blockIdx.y * CHUNK;
    const int col = tid * 2;                 // vertical ownership: cols col,col+1

    // 1-D gaussian from window row 5: w2d[5][j] = g5*g[j], g5 = sqrt(w2d[5][5]).
    float g[WS];
    {
        const float g5  = sqrtf(window[5 * WS + 5]);
        const float inv = 1.0f / g5;
#pragma unroll
        for (int j = 0; j < WS; ++j) g[j] = window[5 * WS + j] * inv;
    }
    const float C1v = 0.01f * 0.01f;
    const float C2v = 0.03f * 0.03f;

    const float* __restrict__ p1 = img1 + (size_t)bc * (IMG_H * IMG_W);
    const float* __restrict__ p2 = img2 + (size_t)bc * (IMG_H * IMG_W);

    // step-invariant LDS byte offsets
    const unsigned woffA = swz8(col + 6);      // write col   (E = 2t+6)
    const unsigned woffB = swz8(col + 7);      // write col+1 (E = 2t+7)
    const int q  = tid & 127;                  // horizontal: col quad 4q..4q+3
    const int jj = tid >> 7;                   // horizontal: row pair 0/1
    unsigned roff[14];                         // reads: E = 4q+1 .. 4q+14
#pragma unroll
    for (int m = 0; m < 14; ++m) roff[m] = swz8(4 * q + 1 + m);

    // zero halo elements once: E in {0..5, 518..523} per region (96 stores)
    if (tid < 96) {
        const int pj = tid / 12, h = tid % 12;
        const int E  = (h < 6) ? h : (512 + h);
        *(v2f*)(lds + pj * PLANE_B + swz8(E)) = (v2f)(0.0f);
    }
    __syncthreads();

    // raw register ring: slot i holds row R-5+i (after the shift at step base R)
    v2f rx1[RING], rx2[RING];
#pragma unroll
    for (int i = 0; i < RING; ++i) { rx1[i] = (v2f)(0.0f); rx2[i] = (v2f)(0.0f); }

    // warm-up: slots 4..13 <- rows r0-5 .. r0+4
#pragma unroll
    for (int i = 0; i < 10; ++i) {
        const int rr = r0 - PAD + i;
        v2f u1 = (v2f)(0.0f), u2 = (v2f)(0.0f);
        if (rr >= 0 && rr < IMG_H) {               // uniform branch
            u1 = *(const v2f*)(p1 + rr * IMG_W + col);
            u2 = *(const v2f*)(p2 + rr * IMG_W + col);
        }
        rx1[4 + i] = u1; rx2[4 + i] = u2;
    }

    float acc = 0.0f;

    for (int step = 0; step < CHUNK / 4; ++step) {
        const int R = r0 + step * 4;           // output rows R..R+3 this step

        // shift ring by 4
#pragma unroll
        for (int i = 0; i < RING - 4; ++i) { rx1[i] = rx1[i + 4]; rx2[i] = rx2[i + 4]; }
        // load rows R+5..R+8 -> slots 10..13
#pragma unroll
        for (int j = 0; j < 4; ++j) {
            const int rr = R + PAD + j;
            v2f u1 = (v2f)(0.0f), u2 = (v2f)(0.0f);
            if (rr < IMG_H) {                  // uniform branch
                u1 = *(const v2f*)(p1 + rr * IMG_W + col);
                u2 = *(const v2f*)(p2 + rr * IMG_W + col);
            }
            rx1[10 + j] = u1; rx2[10 + j] = u2;
        }

        // vertical gaussian sums: 4 planes x 4 rows, packed over the col pair.
        // (X1*X1+X2*X2 and X1*X2 per slot are CSE'd across the 4 rows.)
        v2f va[4][4];
#pragma unroll
        for (int p = 0; p < 4; ++p)
#pragma unroll
            for (int k = 0; k < 4; ++k) va[p][k] = (v2f)(0.0f);
#pragma unroll
        for (int k = 0; k < 4; ++k) {
#pragma unroll
            for (int i = 0; i < WS; ++i) {
                const v2f w  = (v2f)(g[i]);
                const v2f X1 = rx1[i + k], X2 = rx2[i + k];
                va[0][k] = vfma(w, X1, va[0][k]);
                va[1][k] = vfma(w, X2, va[1][k]);
                va[2][k] = vfma(w, vfma(X1, X1, X2 * X2), va[2][k]);
                va[3][k] = vfma(w, X1 * X2, va[3][k]);
            }
        }
        // repack {col-packed rows} -> {row-pair packed cols} and store
#pragma unroll
        for (int jp = 0; jp < 2; ++jp) {
#pragma unroll
            for (int p = 0; p < 4; ++p) {
                char* base = lds + (jp * 4 + p) * PLANE_B;
                *(v2f*)(base + woffA) = (v2f){va[p][2 * jp].x, va[p][2 * jp + 1].x};
                *(v2f*)(base + woffB) = (v2f){va[p][2 * jp].y, va[p][2 * jp + 1].y};
            }
        }
        __syncthreads();

        // horizontal conv + SSIM: 4 cols (quad q), row pair jj (rows R+2jj, +1)
        v2f h[4][4];                           // [plane][d]
#pragma unroll
        for (int p = 0; p < 4; ++p) {
            const char* base = lds + (jj * 4 + p) * PLANE_B;
            v2f r[14];
#pragma unroll
            for (int m = 0; m < 14; ++m) r[m] = *(const v2f*)(base + roff[m]);
#pragma unroll
            for (int d = 0; d < 4; ++d) {
                v2f s = (v2f)(0.0f);
#pragma unroll
                for (int i = 0; i < WS; ++i) s = vfma((v2f)(g[i]), r[d + i], s);
                h[p][d] = s;
            }
        }
#pragma unroll
        for (int d = 0; d < 4; ++d) {
            const v2f mu1 = h[0][d], mu2 = h[1][d];
            const v2f hs  = h[2][d], hp  = h[3][d];
            const v2f mu1s = mu1 * mu1;
            const v2f mu2s = mu2 * mu2;
            const v2f mu12 = mu1 * mu2;
            const v2f sgs  = hs - mu1s - mu2s;       // sigma1^2 + sigma2^2
            const v2f sg12 = hp - mu12;
            const v2f num  = (2.f * mu12 + (v2f)(C1v)) * (2.f * sg12 + (v2f)(C2v));
            const v2f den  = (mu1s + mu2s + (v2f)(C1v)) * (sgs + (v2f)(C2v));
            v2f r = {__builtin_amdgcn_rcpf(den.x), __builtin_amdgcn_rcpf(den.y)};
            r = r * vfma(-den, r, (v2f)(2.0f));      // Newton -> ~1 ulp
            acc = fmaf(num.x, r.x, acc);
            acc = fmaf(num.y, r.y, acc);
        }
        __syncthreads();   // before LDS is overwritten next step
    }

    // block reduction -> single atomic per block (pre-scaled by 1/Npx)
#pragma unroll
    for (int off = 32; off > 0; off >>= 1)
        acc += __shfl_down(acc, off);
    if ((tid & 63) == 0) wred[tid >> 6] = acc;
    __syncthreads();
    if (tid == 0) {
        const float s = (wred[0] + wred[1]) + (wred[2] + wred[3]);
        atomicAdd(out, s * INV_NPX);
    }
}

extern "C" void kernel_launch(void* const* d_in, const int* in_sizes, int n_in,
                              void* d_out, int out_size, void* d_ws, size_t ws_size,
                              hipStream_t stream) {
    const float* img1   = (const float*)d_in[0];
    const float* img2   = (const float*)d_in[1];
    const float* window = (const float*)d_in[2];
    float* out = (float*)d_out;

    hipMemsetAsync(out, 0, sizeof(float), stream);   // graph-capturable
    dim3 grid(N_IMG, NCHUNK);
    ssim_partial_kernel<<<grid, 256, 0, stream>>>(img1, img2, window, out);
}

// Round 9
// 139.339 us; speedup vs baseline: 1.6981x; 1.0191x over previous
//
#include <hip/hip_runtime.h>

// SSIM (B=16, C=3, H=W=512, fp32) -> scalar mean.
// v9: v8 structure with a PROVEN-by-enumeration LDS swizzle: P = E + (E>>2).
//  - Reads (lane-stride 4 elements): P = 5l+c -> 10l mod 32 covers all 16 even
//    residues per 16-lane phase -> 32 dwords hit 32 distinct banks: conflict-free.
//  - Writes (lane-stride 2 elements): 4 dwords/bank over the wave (floor), one
//    doubled bank-pair per phase (~2 cyc residual) -- negligible at 16/72 ops.
//  - Everything else identical to v8 (4-row steps, col-pair vertical ring,
//    col-quad horizontal, packed fp32, fused atomicAdd reduction).

typedef float v2f __attribute__((ext_vector_type(2)));

#define IMG_H 512
#define IMG_W 512
#define N_IMG 48                    // B*C
#define WS 11
#define PAD 5
#define CHUNK 16                    // output rows per block
#define NCHUNK (IMG_H / CHUNK)      // 32
#define RING 14                     // rows held in registers
#define PLANE_B 5248                // bytes per (pair,plane) region (max off 5232)
#define INV_NPX (1.0f / (48.0f * 512.0f * 512.0f))

// swizzled byte offset of element E (element = 8B v2f {row_even,row_odd})
__device__ __forceinline__ unsigned swz8(int E) {
    return (unsigned)((E + (E >> 2)) * 8);
}
__device__ __forceinline__ v2f vfma(v2f a, v2f b, v2f c) {
    return __builtin_elementwise_fma(a, b, c);
}

__global__ __launch_bounds__(256, 3) void ssim_partial_kernel(
    const float* __restrict__ img1,
    const float* __restrict__ img2,
    const float* __restrict__ window,
    float* __restrict__ out)
{
    __shared__ __align__(16) char lds[8 * PLANE_B];   // region (pair*4+plane)
    __shared__ float wred[4];

    const int tid = threadIdx.x;
    const int bc  = blockIdx.x;              // image*channel 0..47
    const int r0  = blockIdx.y * CHUNK;
    const int col = tid * 2;                 // vertical ownership: cols col,col+1

    // 1-D gaussian from window row 5: w2d[5][j] = g5*g[j], g5 = sqrt(w2d[5][5]).
    float g[WS];
    {
        const float g5  = sqrtf(window[5 * WS + 5]);
        const float inv = 1.0f / g5;
#pragma unroll
        for (int j = 0; j < WS; ++j) g[j] = window[5 * WS + j] * inv;
    }
    const float C1v = 0.01f * 0.01f;
    const float C2v = 0.03f * 0.03f;

    const float* __restrict__ p1 = img1 + (size_t)bc * (IMG_H * IMG_W);
    const float* __restrict__ p2 = img2 + (size_t)bc * (IMG_H * IMG_W);

    // step-invariant LDS byte offsets
    const unsigned woffA = swz8(col + 6);      // write col   (E = 2t+6)
    const unsigned woffB = swz8(col + 7);      // write col+1 (E = 2t+7)
    const int q  = tid & 127;                  // horizontal: col quad 4q..4q+3
    const int jj = tid >> 7;                   // horizontal: row pair 0/1
    unsigned roff[14];                         // reads: E = 4q+1 .. 4q+14
#pragma unroll
    for (int m = 0; m < 14; ++m) roff[m] = swz8(4 * q + 1 + m);

    // zero halo elements once: E in {0..5, 518..523} per region (96 stores)
    if (tid < 96) {
        const int pj = tid / 12, h = tid % 12;
        const int E  = (h < 6) ? h : (512 + h);
        *(v2f*)(lds + pj * PLANE_B + swz8(E)) = (v2f)(0.0f);
    }
    __syncthreads();

    // raw register ring: slot i holds row R-5+i (after the shift at step base R)
    v2f rx1[RING], rx2[RING];
#pragma unroll
    for (int i = 0; i < RING; ++i) { rx1[i] = (v2f)(0.0f); rx2[i] = (v2f)(0.0f); }

    // warm-up: slots 4..13 <- rows r0-5 .. r0+4
#pragma unroll
    for (int i = 0; i < 10; ++i) {
        const int rr = r0 - PAD + i;
        v2f u1 = (v2f)(0.0f), u2 = (v2f)(0.0f);
        if (rr >= 0 && rr < IMG_H) {               // uniform branch
            u1 = *(const v2f*)(p1 + rr * IMG_W + col);
            u2 = *(const v2f*)(p2 + rr * IMG_W + col);
        }
        rx1[4 + i] = u1; rx2[4 + i] = u2;
    }

    float acc = 0.0f;

    for (int step = 0; step < CHUNK / 4; ++step) {
        const int R = r0 + step * 4;           // output rows R..R+3 this step

        // shift ring by 4
#pragma unroll
        for (int i = 0; i < RING - 4; ++i) { rx1[i] = rx1[i + 4]; rx2[i] = rx2[i + 4]; }
        // load rows R+5..R+8 -> slots 10..13
#pragma unroll
        for (int j = 0; j < 4; ++j) {
            const int rr = R + PAD + j;
            v2f u1 = (v2f)(0.0f), u2 = (v2f)(0.0f);
            if (rr < IMG_H) {                  // uniform branch
                u1 = *(const v2f*)(p1 + rr * IMG_W + col);
                u2 = *(const v2f*)(p2 + rr * IMG_W + col);
            }
            rx1[10 + j] = u1; rx2[10 + j] = u2;
        }

        // vertical gaussian sums: 4 planes x 4 rows, packed over the col pair.
        // (X1*X1+X2*X2 and X1*X2 per slot are CSE'd across the 4 rows.)
        v2f va[4][4];
#pragma unroll
        for (int p = 0; p < 4; ++p)
#pragma unroll
            for (int k = 0; k < 4; ++k) va[p][k] = (v2f)(0.0f);
#pragma unroll
        for (int k = 0; k < 4; ++k) {
#pragma unroll
            for (int i = 0; i < WS; ++i) {
                const v2f w  = (v2f)(g[i]);
                const v2f X1 = rx1[i + k], X2 = rx2[i + k];
                va[0][k] = vfma(w, X1, va[0][k]);
                va[1][k] = vfma(w, X2, va[1][k]);
                va[2][k] = vfma(w, vfma(X1, X1, X2 * X2), va[2][k]);
                va[3][k] = vfma(w, X1 * X2, va[3][k]);
            }
        }
        // repack {col-packed rows} -> {row-pair packed cols} and store
#pragma unroll
        for (int jp = 0; jp < 2; ++jp) {
#pragma unroll
            for (int p = 0; p < 4; ++p) {
                char* base = lds + (jp * 4 + p) * PLANE_B;
                *(v2f*)(base + woffA) = (v2f){va[p][2 * jp].x, va[p][2 * jp + 1].x};
                *(v2f*)(base + woffB) = (v2f){va[p][2 * jp].y, va[p][2 * jp + 1].y};
            }
        }
        __syncthreads();

        // horizontal conv + SSIM: 4 cols (quad q), row pair jj (rows R+2jj, +1)
        v2f h[4][4];                           // [plane][d]
#pragma unroll
        for (int p = 0; p < 4; ++p) {
            const char* base = lds + (jj * 4 + p) * PLANE_B;
            v2f r[14];
#pragma unroll
            for (int m = 0; m < 14; ++m) r[m] = *(const v2f*)(base + roff[m]);
#pragma unroll
            for (int d = 0; d < 4; ++d) {
                v2f s = (v2f)(0.0f);
#pragma unroll
                for (int i = 0; i < WS; ++i) s = vfma((v2f)(g[i]), r[d + i], s);
                h[p][d] = s;
            }
        }
#pragma unroll
        for (int d = 0; d < 4; ++d) {
            const v2f mu1 = h[0][d], mu2 = h[1][d];
            const v2f hs  = h[2][d], hp  = h[3][d];
            const v2f mu1s = mu1 * mu1;
            const v2f mu2s = mu2 * mu2;
            const v2f mu12 = mu1 * mu2;
            const v2f sgs  = hs - mu1s - mu2s;       // sigma1^2 + sigma2^2
            const v2f sg12 = hp - mu12;
            const v2f num  = (2.f * mu12 + (v2f)(C1v)) * (2.f * sg12 + (v2f)(C2v));
            const v2f den  = (mu1s + mu2s + (v2f)(C1v)) * (sgs + (v2f)(C2v));
            v2f r = {__builtin_amdgcn_rcpf(den.x), __builtin_amdgcn_rcpf(den.y)};
            r = r * vfma(-den, r, (v2f)(2.0f));      // Newton -> ~1 ulp
            acc = fmaf(num.x, r.x, acc);
            acc = fmaf(num.y, r.y, acc);
        }
        __syncthreads();   // before LDS is overwritten next step
    }

    // block reduction -> single atomic per block (pre-scaled by 1/Npx)
#pragma unroll
    for (int off = 32; off > 0; off >>= 1)
        acc += __shfl_down(acc, off);
    if ((tid & 63) == 0) wred[tid >> 6] = acc;
    __syncthreads();
    if (tid == 0) {
        const float s = (wred[0] + wred[1]) + (wred[2] + wred[3]);
        atomicAdd(out, s * INV_NPX);
    }
}

extern "C" void kernel_launch(void* const* d_in, const int* in_sizes, int n_in,
                              void* d_out, int out_size, void* d_ws, size_t ws_size,
                              hipStream_t stream) {
    const float* img1   = (const float*)d_in[0];
    const float* img2   = (const float*)d_in[1];
    const float* window = (const float*)d_in[2];
    float* out = (float*)d_out;

    hipMemsetAsync(out, 0, sizeof(float), stream);   // graph-capturable
    dim3 grid(N_IMG, NCHUNK);
    ssim_partial_kernel<<<grid, 256, 0, stream>>>(img1, img2, window, out);
}